// Round 3
// baseline (5657.962 us; speedup 1.0000x reference)
//
#include <hip/hip_runtime.h>

#define BATCH 512
#define TT 64
#define II 128

// ---------------- workspace layout (floats) ----------------
#define OFF_Wr_e0 0                         // [512][256] rows: [Wih0(x,pad)|Whh0(h0)]
#define OFF_Wr_e1 (OFF_Wr_e0 + 512*256)     // [512][256] rows: [Wih1(h0)|Whh1(h1)]
#define OFF_Wr_d1 (OFF_Wr_e1 + 512*256)     // [512][256] rows: [dWih1(h0)|dWhh1(h1)]
#define OFF_bs0e  (OFF_Wr_d1 + 512*256)
#define OFF_bs1e  (OFF_bs0e + 512)
#define OFF_bs0d  (OFF_bs1e + 512)
#define OFF_bs1d  (OFF_bs0d + 512)
#define OFF_xprojT (OFF_bs1d + 512)          // [B][64j][128e]
#define OFF_hexp   (OFF_xprojT + BATCH*8192) // [B][64t][128k]
#define OFF_hprojT (OFF_hexp + BATCH*8192)   // [B][128kk][64t]

struct Params {
  const float* input;
  const float *eWih0, *eWhh0, *ebih0, *ebhh0, *eWih1, *eWhh1, *ebih1, *ebhh1;
  const float *dWih0, *dWhh0, *dbih0, *dbhh0, *dWih1, *dWhh1, *dbih1, *dbhh1;
  const float *aW1, *ab1, *aW2, *ab2;
  const float *adW1, *adb1, *adW2, *adb2;
  const float *dinW, *dinb, *projW, *projb;
  float* ws;
  float* out;
};

#define L2E 1.4426950408889634f

__device__ __forceinline__ float exp2f_(float x){ return __builtin_amdgcn_exp2f(x); }
__device__ __forceinline__ float rcp_(float x){ return __builtin_amdgcn_rcpf(x); }
__device__ __forceinline__ float fast_tanh(float x){
  float t = exp2f_(x * 2.8853900817779268f);   // e^{2x}
  return 1.f - 2.f * rcp_(t + 1.f);
}
__device__ __forceinline__ float sigm(float x){
  return rcp_(1.f + exp2f_(-x * L2E));
}
__device__ __forceinline__ float wave_max(float v){
  #pragma unroll
  for (int o = 32; o > 0; o >>= 1) v = fmaxf(v, __shfl_xor(v, o, 64));
  return v;
}
__device__ __forceinline__ float wave_sum(float v){
  #pragma unroll
  for (int o = 32; o > 0; o >>= 1) v += __shfl_xor(v, o, 64);
  return v;
}

// ---------------- prep: build row-major fused weight rows + bias sums -------
__global__ __launch_bounds__(256) void k_prep(Params p){
  float* ws = p.ws;
  const int gid = blockIdx.x*256 + threadIdx.x;
  const int gsz = gridDim.x*256;
  for (int i = gid; i < 512*256; i += gsz){
    const int j = i >> 8, k = i & 255;
    ws[OFF_Wr_e0 + i] = (k < 128) ? ((k < 127) ? p.eWih0[j*127 + k] : 0.f)
                                  : p.eWhh0[j*128 + (k-128)];
    ws[OFF_Wr_e1 + i] = (k < 128) ? p.eWih1[j*128 + k] : p.eWhh1[j*128 + (k-128)];
    ws[OFF_Wr_d1 + i] = (k < 128) ? p.dWih1[j*128 + k] : p.dWhh1[j*128 + (k-128)];
  }
  for (int i = gid; i < 512; i += gsz){
    ws[OFF_bs0e+i] = p.ebih0[i]+p.ebhh0[i];
    ws[OFF_bs1e+i] = p.ebih1[i]+p.ebhh1[i];
    ws[OFF_bs0d+i] = p.dbih0[i]+p.dbhh0[i];
    ws[OFF_bs1d+i] = p.dbih1[i]+p.dbhh1[i];
  }
}

// ---------------- xprojT[b][j][e] = ab1[j] + sum_k inp[b,k,1+e]*W1x[j,k] ----
__global__ __launch_bounds__(256) void k_xproj(Params p){
  __shared__ float xin[64][128];   // [k][e]
  __shared__ float w1x[64][64];    // [j][k]
  __shared__ float b1s[64];
  const int b = blockIdx.x, tid = threadIdx.x;
  const float* inb = p.input + (size_t)b*(TT*II);
  for (int i = tid; i < 64*128; i += 256){
    const int k = i >> 7, e = i & 127;
    xin[k][e] = (e < 127) ? inb[k*II + 1 + e] : 0.f;
  }
  for (int i = tid; i < 64*64; i += 256){
    const int j = i >> 6, k = i & 63;
    w1x[j][k] = p.aW1[j*320 + 256 + k];
  }
  if (tid < 64) b1s[tid] = p.ab1[tid];
  __syncthreads();
  float* outb = p.ws + OFF_xprojT + (size_t)b*8192;
  for (int i = tid; i < 64*128; i += 256){
    const int j = i >> 7, e = i & 127;
    float acc = b1s[j];
    #pragma unroll 8
    for (int k = 0; k < 64; ++k) acc += xin[k][e] * w1x[j][k];
    outb[i] = acc;
  }
}

// ---------------- hprojT[b][kk][t] = adb1[kk] + sum_k hexp[b][t][k]*adW1[kk][256+k]
__global__ __launch_bounds__(256) void k_hproj(Params p){
  __shared__ float hx[64][129];   // [t][k] padded
  __shared__ float bs[128];
  const int b = blockIdx.x, tid = threadIdx.x;
  const float* hb = p.ws + OFF_hexp + (size_t)b*8192;
  for (int i = tid; i < 64*128; i += 256){
    hx[i>>7][i&127] = hb[i];
  }
  if (tid < 128) bs[tid] = p.adb1[tid];
  __syncthreads();
  float* outb = p.ws + OFF_hprojT + (size_t)b*8192;
  for (int i = tid; i < 128*64; i += 256){
    const int kk = i >> 6, t2 = i & 63;
    const float* w = p.adW1 + kk*384 + 256;
    float acc = bs[kk];
    #pragma unroll 8
    for (int k = 0; k < 128; ++k) acc += hx[t2][k] * w[k];
    outb[i] = acc;
  }
}

// ---------------- encoder: 128 blocks x 4 batches, 1024 threads -------------
// dynamic LDS (floats): xp 32768 | Se 2048 | c0 512 | gpA 2048 | gpB 2048
//                       scr 1024 | g01 256 | w2 64 | pm 8 | ps 8   = 40784
#define ENC_LDS_FLOATS 40784
__global__ __launch_bounds__(1024, 4) void k_enc(Params p){
  extern __shared__ float sm[];
  float* xp  = sm;             // [bb][j][e] 4x64x128
  float* Se  = xp + 32768;     // [bb][ x |h0 |h1 |c1 ] 4x512
  float* c0  = Se + 2048;
  float* gpA = c0 + 512;       // [bb][512]
  float* gpB = gpA + 2048;
  float* scr = gpB + 2048;     // shared partial buffer
  float* g01 = scr + 1024;     // [bb][64]
  float* w2  = g01 + 256;
  float* pm  = w2 + 64;
  float* psu = pm + 8;
  const int tid = threadIdx.x;
  const int b0 = blockIdx.x * 4;
  float* ws = p.ws;

  { // load xprojT for 4 batches (contiguous) into LDS
    const float4* xsrc = (const float4*)(ws + OFF_xprojT + (size_t)b0*8192);
    float4* xdst = (float4*)xp;
    for (int i = tid; i < 8192; i += 1024) xdst[i] = xsrc[i];
  }
  for (int i = tid; i < 2048; i += 1024) Se[i] = 0.f;
  if (tid < 512) c0[tid] = 0.f;
  if (tid < 64) w2[tid] = p.aW2[tid];
  const float b2 = p.ab2[0];
  const int j = tid & 511, kh = tid >> 9;
  const float bias0 = ws[OFF_bs0e + j];
  const float bias1 = ws[OFF_bs1e + j];
  const int jj = tid & 63, bb1 = (tid>>6)&3, kq = tid >> 8;      // E1 map
  const int e2 = tid & 127, bb2 = (tid>>7)&3, jh = tid >> 9;     // E2 map
  const int hf = (tid>>6)&1;
  __syncthreads();

  for (int t = 0; t < TT; ++t){
    // --- E1: g01 partial = sum_k S1[bb][k]*aW1[jj][k] over k-quarter
    {
      const float4* wr = (const float4*)(p.aW1 + jj*320 + kq*64);
      const float4* s1 = (const float4*)(Se + bb1*512 + 256 + kq*64);
      float a = 0.f;
      #pragma unroll 8
      for (int g = 0; g < 16; ++g){
        const float4 w = wr[g], x = s1[g];
        a += w.x*x.x + w.y*x.y + w.z*x.z + w.w*x.w;
      }
      scr[kq*256 + bb1*64 + jj] = a;
    }
    __syncthreads();
    if (tid < 256) g01[tid] = scr[tid] + scr[256+tid] + scr[512+tid] + scr[768+tid];
    __syncthreads();
    // --- E2a: logit partials over j-half
    {
      const float* xpe = xp + bb2*8192 + e2;
      const float* gg = g01 + bb2*64 + jh*32;
      const float* w2p = w2 + jh*32;
      float acc = 0.f;
      #pragma unroll 8
      for (int q = 0; q < 32; ++q)
        acc += w2p[q] * fast_tanh(xpe[(jh*32+q)*128] + gg[q]);
      scr[jh*512 + bb2*128 + e2] = acc;
    }
    __syncthreads();
    // --- E2b: combine + per-wave softmax partials (dup over jh, benign)
    float acc_l;
    {
      acc_l = scr[bb2*128 + e2] + scr[512 + bb2*128 + e2] + b2;
      if (e2 == 127) acc_l = -3.0e38f;
      const float m = wave_max(acc_l);
      const float pe = exp2f_((acc_l - m)*L2E);
      const float s = wave_sum(pe);
      if ((tid & 63) == 0){ pm[bb2*2+hf] = m; psu[bb2*2+hf] = s; }
    }
    __syncthreads();
    // --- E2c: finish softmax, Se.x = a * x_t (dup writes identical)
    {
      const float m0 = pm[bb2*2], m1 = pm[bb2*2+1];
      const float gm = fmaxf(m0, m1);
      const float tot = psu[bb2*2]*exp2f_((m0-gm)*L2E) + psu[bb2*2+1]*exp2f_((m1-gm)*L2E);
      const float a = exp2f_((acc_l - gm)*L2E) * rcp_(tot);
      float xv = 0.f;
      if (e2 < 127) xv = p.input[(size_t)(b0+bb2)*8192 + t*128 + 1 + e2] * a;
      Se[bb2*512 + e2] = xv;
    }
    __syncthreads();
    // --- E3: layer0 gates, rows Wr_e0, operand Se[0..255] (x|h0)
    {
      const float4* r  = (const float4*)(ws + OFF_Wr_e0 + (j<<8) + (kh<<7));
      const float4* x0 = (const float4*)(Se + (kh<<7));
      const float4* x1 = (const float4*)(Se + 512 + (kh<<7));
      const float4* x2 = (const float4*)(Se + 1024 + (kh<<7));
      const float4* x3 = (const float4*)(Se + 1536 + (kh<<7));
      float a0,a1,a2,a3; a0=a1=a2=a3 = kh ? 0.f : bias0;
      #pragma unroll 8
      for (int kg = 0; kg < 32; ++kg){
        const float4 w = r[kg];
        const float4 v0=x0[kg], v1=x1[kg], v2=x2[kg], v3=x3[kg];
        a0 += w.x*v0.x + w.y*v0.y + w.z*v0.z + w.w*v0.w;
        a1 += w.x*v1.x + w.y*v1.y + w.z*v1.z + w.w*v1.w;
        a2 += w.x*v2.x + w.y*v2.y + w.z*v2.z + w.w*v2.w;
        a3 += w.x*v3.x + w.y*v3.y + w.z*v3.z + w.w*v3.w;
      }
      float* gp = kh ? gpB : gpA;
      gp[j] = a0; gp[512+j] = a1; gp[1024+j] = a2; gp[1536+j] = a3;
    }
    __syncthreads();
    // --- A0: update h0, c0
    if (tid < 512){
      const int bb = tid>>7, u = tid&127;
      const float* gA = gpA + bb*512; const float* gB = gpB + bb*512;
      const float gi = gA[u]+gB[u], gf = gA[128+u]+gB[128+u];
      const float gg2 = gA[256+u]+gB[256+u], go = gA[384+u]+gB[384+u];
      const float c = sigm(gf)*c0[tid] + sigm(gi)*fast_tanh(gg2);
      c0[tid] = c;
      Se[bb*512 + 128 + u] = sigm(go)*fast_tanh(c);
    }
    __syncthreads();
    // --- E4: layer1 gates, rows Wr_e1, operand Se[128..383] (h0|h1)
    {
      const float4* r  = (const float4*)(ws + OFF_Wr_e1 + (j<<8) + (kh<<7));
      const float4* x0 = (const float4*)(Se + 128 + (kh<<7));
      const float4* x1 = (const float4*)(Se + 640 + (kh<<7));
      const float4* x2 = (const float4*)(Se + 1152 + (kh<<7));
      const float4* x3 = (const float4*)(Se + 1664 + (kh<<7));
      float a0,a1,a2,a3; a0=a1=a2=a3 = kh ? 0.f : bias1;
      #pragma unroll 8
      for (int kg = 0; kg < 32; ++kg){
        const float4 w = r[kg];
        const float4 v0=x0[kg], v1=x1[kg], v2=x2[kg], v3=x3[kg];
        a0 += w.x*v0.x + w.y*v0.y + w.z*v0.z + w.w*v0.w;
        a1 += w.x*v1.x + w.y*v1.y + w.z*v1.z + w.w*v1.w;
        a2 += w.x*v2.x + w.y*v2.y + w.z*v2.z + w.w*v2.w;
        a3 += w.x*v3.x + w.y*v3.y + w.z*v3.z + w.w*v3.w;
      }
      float* gp = kh ? gpB : gpA;
      gp[j] = a0; gp[512+j] = a1; gp[1024+j] = a2; gp[1536+j] = a3;
    }
    __syncthreads();
    // --- A1: update h1, c1, write hexp
    if (tid < 512){
      const int bb = tid>>7, u = tid&127;
      const float* gA = gpA + bb*512; const float* gB = gpB + bb*512;
      const float gi = gA[u]+gB[u], gf = gA[128+u]+gB[128+u];
      const float gg2 = gA[256+u]+gB[256+u], go = gA[384+u]+gB[384+u];
      const float c = sigm(gf)*Se[bb*512+384+u] + sigm(gi)*fast_tanh(gg2);
      Se[bb*512+384+u] = c;
      const float h = sigm(go)*fast_tanh(c);
      Se[bb*512+256+u] = h;
      ws[OFF_hexp + (size_t)(b0+bb)*8192 + t*128 + u] = h;
    }
    __syncthreads();
  }
}

// ---------------- decoder: 128 blocks x 4 batches, 1024 threads -------------
// dynamic LDS (floats): hp 32768 | Sd 1536 | c0 512 | gpA 2048 | gpB 2048
//                       scr 1024 | g01 512 | wd2 128 | dins 8   = 40584
#define DEC_LDS_FLOATS 40584
__global__ __launch_bounds__(1024, 4) void k_dec(Params p){
  extern __shared__ float sm[];
  float* hp  = sm;            // [bb][kk][t'] 4x128x64
  float* Sd  = hp + 32768;    // [bb][ h0 |h1 |c1 ] 4x384
  float* c0  = Sd + 1536;
  float* gpA = c0 + 512;
  float* gpB = gpA + 2048;
  float* scr = gpB + 2048;    // D2a partials; then parts[bb][128]
  float* g01 = scr + 1024;    // D1 out [bb][128]; reused as abuf[bb][64]
  float* wd2 = g01 + 512;
  float* dins= wd2 + 128;
  const int tid = threadIdx.x;
  const int b0 = blockIdx.x * 4;
  float* ws = p.ws;

  { // load hprojT for 4 batches into LDS
    const float4* hsrc = (const float4*)(ws + OFF_hprojT + (size_t)b0*8192);
    float4* hdst = (float4*)hp;
    for (int i = tid; i < 8192; i += 1024) hdst[i] = hsrc[i];
  }
  for (int i = tid; i < 1536; i += 1024) Sd[i] = 0.f;
  if (tid < 512) c0[tid] = 0.f;
  if (tid < 128) wd2[tid] = p.adW2[tid];
  const int j = tid & 511, kh = tid >> 9;
  const float bias0d = ws[OFF_bs0d + j];
  const float bias1d = ws[OFF_bs1d + j];
  const float dW0j = p.dWih0[j];
  const int o = tid & 511, bbD = o>>7, kkD = o&127;      // D1 map
  const int l = tid & 63, wv = tid >> 6;
  const int bbA = wv>>2, kqA = wv&3;                     // D2a map
  const int th = tid>>9, bbC = (tid>>7)&3, hC = tid&127; // D2c map
  const float dinw0 = p.dinW[l], dinw1 = p.dinW[64+l];
  const float dinw128 = p.dinW[128], dinbv = p.dinb[0];
  const float bd2 = p.adb2[0];
  const float pw0 = p.projW[l], pw1 = p.projW[64+l];
  const float pw2 = p.projW[128+l], pw3 = p.projW[192+l];
  const float pb = p.projb[0];
  __syncthreads();

  for (int t = 0; t < TT; ++t){
    // --- D1: g01[bb][kk] partial over K-half of [h1|c1], rows adW1[kk][0..255]
    {
      const float4* wr = (const float4*)(p.adW1 + kkD*384 + (kh<<7));
      const float4* sx = (const float4*)(Sd + bbD*384 + 128 + (kh<<7));
      float a = 0.f;
      #pragma unroll 8
      for (int kg = 0; kg < 32; ++kg){
        const float4 w = wr[kg], x = sx[kg];
        a += w.x*x.x + w.y*x.y + w.z*x.z + w.w*x.w;
      }
      (kh ? gpB : gpA)[o] = a;
    }
    __syncthreads();
    g01[tid&511] = gpA[tid&511] + gpB[tid&511];   // dup identical
    __syncthreads();
    // --- D2a: logit partials; wave=(bb,kq), lane=t'
    {
      const float* hpb = hp + bbA*8192 + l;
      const float* gg = g01 + bbA*128 + kqA*32;
      const float* w2p = wd2 + kqA*32;
      float acc = 0.f;
      #pragma unroll 8
      for (int q = 0; q < 32; ++q)
        acc += w2p[q] * fast_tanh(hpb[(kqA*32+q)*64] + gg[q]);
      scr[kqA*256 + bbA*64 + l] = acc;
    }
    __syncthreads();
    // --- D2b: combine + softmax over t' (dup x4, writes identical)
    {
      const int q = tid & 255;
      float acc = scr[q] + scr[256+q] + scr[512+q] + scr[768+q] + bd2;
      const float m = wave_max(acc);
      const float pe = exp2f_((acc - m)*L2E);
      const float s = wave_sum(pe);
      g01[q] = pe * rcp_(s);          // abuf
    }
    __syncthreads();
    // --- D2c: parts partial = sum_{t'-half} a[t'] * hexp[b][t'][h]
    {
      const float* he = ws + OFF_hexp + (size_t)(b0+bbC)*8192 + hC;
      const float* av = g01 + bbC*64 + th*32;
      float acc = 0.f;
      #pragma unroll 8
      for (int q = 0; q < 32; ++q)
        acc += av[q] * he[(th*32+q)*128];
      (th ? gpB : gpA)[bbC*128 + hC] = acc;
    }
    __syncthreads();
    scr[tid&511] = gpA[tid&511] + gpB[tid&511];   // parts, dup identical
    __syncthreads();
    // --- D2d: din per batch
    if (wv < 4){
      float v = scr[wv*128 + l]*dinw0 + scr[wv*128 + 64 + l]*dinw1;
      v = wave_sum(v);
      if (l == 0){
        const float xd = p.input[(size_t)(b0+wv)*8192 + t*128];
        dins[wv] = v + xd*dinw128 + dinbv;
      }
    }
    __syncthreads();
    // --- D3: layer0 gates (K=128 h0 + rank-1 din), rows dWhh0
    {
      const float4* wr = (const float4*)(p.dWhh0 + (j<<7) + (kh<<6));
      const float4* x0 = (const float4*)(Sd + (kh<<6));
      const float4* x1 = (const float4*)(Sd + 384 + (kh<<6));
      const float4* x2 = (const float4*)(Sd + 768 + (kh<<6));
      const float4* x3 = (const float4*)(Sd + 1152 + (kh<<6));
      float a0,a1,a2,a3;
      if (kh){ a0=a1=a2=a3=0.f; }
      else {
        a0 = bias0d + dins[0]*dW0j; a1 = bias0d + dins[1]*dW0j;
        a2 = bias0d + dins[2]*dW0j; a3 = bias0d + dins[3]*dW0j;
      }
      #pragma unroll 8
      for (int kg = 0; kg < 16; ++kg){
        const float4 w = wr[kg];
        const float4 v0=x0[kg], v1=x1[kg], v2=x2[kg], v3=x3[kg];
        a0 += w.x*v0.x + w.y*v0.y + w.z*v0.z + w.w*v0.w;
        a1 += w.x*v1.x + w.y*v1.y + w.z*v1.z + w.w*v1.w;
        a2 += w.x*v2.x + w.y*v2.y + w.z*v2.z + w.w*v2.w;
        a3 += w.x*v3.x + w.y*v3.y + w.z*v3.z + w.w*v3.w;
      }
      float* gp = kh ? gpB : gpA;
      gp[j] = a0; gp[512+j] = a1; gp[1024+j] = a2; gp[1536+j] = a3;
    }
    __syncthreads();
    // --- A2: update h0, c0
    if (tid < 512){
      const int bb = tid>>7, u = tid&127;
      const float* gA = gpA + bb*512; const float* gB = gpB + bb*512;
      const float gi = gA[u]+gB[u], gf = gA[128+u]+gB[128+u];
      const float gg2 = gA[256+u]+gB[256+u], go = gA[384+u]+gB[384+u];
      const float c = sigm(gf)*c0[tid] + sigm(gi)*fast_tanh(gg2);
      c0[tid] = c;
      Sd[bb*384 + u] = sigm(go)*fast_tanh(c);
    }
    __syncthreads();
    // --- D4: layer1 gates (K=256 h0|h1), rows Wr_d1
    {
      const float4* wr = (const float4*)(ws + OFF_Wr_d1 + (j<<8) + (kh<<7));
      const float4* x0 = (const float4*)(Sd + (kh<<7));
      const float4* x1 = (const float4*)(Sd + 384 + (kh<<7));
      const float4* x2 = (const float4*)(Sd + 768 + (kh<<7));
      const float4* x3 = (const float4*)(Sd + 1152 + (kh<<7));
      float a0,a1,a2,a3; a0=a1=a2=a3 = kh ? 0.f : bias1d;
      #pragma unroll 8
      for (int kg = 0; kg < 32; ++kg){
        const float4 w = wr[kg];
        const float4 v0=x0[kg], v1=x1[kg], v2=x2[kg], v3=x3[kg];
        a0 += w.x*v0.x + w.y*v0.y + w.z*v0.z + w.w*v0.w;
        a1 += w.x*v1.x + w.y*v1.y + w.z*v1.z + w.w*v1.w;
        a2 += w.x*v2.x + w.y*v2.y + w.z*v2.z + w.w*v2.w;
        a3 += w.x*v3.x + w.y*v3.y + w.z*v3.z + w.w*v3.w;
      }
      float* gp = kh ? gpB : gpA;
      gp[j] = a0; gp[512+j] = a1; gp[1024+j] = a2; gp[1536+j] = a3;
    }
    __syncthreads();
    // --- A3: update h1, c1
    if (tid < 512){
      const int bb = tid>>7, u = tid&127;
      const float* gA = gpA + bb*512; const float* gB = gpB + bb*512;
      const float gi = gA[u]+gB[u], gf = gA[128+u]+gB[128+u];
      const float gg2 = gA[256+u]+gB[256+u], go = gA[384+u]+gB[384+u];
      const float c = sigm(gf)*Sd[bb*384+256+u] + sigm(gi)*fast_tanh(gg2);
      Sd[bb*384+256+u] = c;
      Sd[bb*384+128+u] = sigm(go)*fast_tanh(c);
    }
    __syncthreads();
  }
  // --- final projection
  if (wv < 4){
    float v = Sd[wv*384+128+l]*pw0 + Sd[wv*384+192+l]*pw1
            + scr[wv*128+l]*pw2 + scr[wv*128+64+l]*pw3;
    v = wave_sum(v);
    if (l == 0) p.out[b0 + wv] = v + pb;
  }
}

extern "C" void kernel_launch(void* const* d_in, const int* in_sizes, int n_in,
                              void* d_out, int out_size, void* d_ws, size_t ws_size,
                              hipStream_t stream){
  Params p;
  p.input = (const float*)d_in[0];
  p.eWih0=(const float*)d_in[1];  p.eWhh0=(const float*)d_in[2];
  p.ebih0=(const float*)d_in[3];  p.ebhh0=(const float*)d_in[4];
  p.eWih1=(const float*)d_in[5];  p.eWhh1=(const float*)d_in[6];
  p.ebih1=(const float*)d_in[7];  p.ebhh1=(const float*)d_in[8];
  p.dWih0=(const float*)d_in[9];  p.dWhh0=(const float*)d_in[10];
  p.dbih0=(const float*)d_in[11]; p.dbhh0=(const float*)d_in[12];
  p.dWih1=(const float*)d_in[13]; p.dWhh1=(const float*)d_in[14];
  p.dbih1=(const float*)d_in[15]; p.dbhh1=(const float*)d_in[16];
  p.aW1=(const float*)d_in[17];   p.ab1=(const float*)d_in[18];
  p.aW2=(const float*)d_in[19];   p.ab2=(const float*)d_in[20];
  p.adW1=(const float*)d_in[21];  p.adb1=(const float*)d_in[22];
  p.adW2=(const float*)d_in[23];  p.adb2=(const float*)d_in[24];
  p.dinW=(const float*)d_in[25];  p.dinb=(const float*)d_in[26];
  p.projW=(const float*)d_in[27]; p.projb=(const float*)d_in[28];
  p.ws = (float*)d_ws;
  p.out = (float*)d_out;

  (void)hipFuncSetAttribute(reinterpret_cast<const void*>(k_enc),
      hipFuncAttributeMaxDynamicSharedMemorySize, ENC_LDS_FLOATS*4);
  (void)hipFuncSetAttribute(reinterpret_cast<const void*>(k_dec),
      hipFuncAttributeMaxDynamicSharedMemorySize, DEC_LDS_FLOATS*4);

  hipLaunchKernelGGL(k_prep,  dim3(128), dim3(256), 0, stream, p);
  hipLaunchKernelGGL(k_xproj, dim3(BATCH), dim3(256), 0, stream, p);
  hipLaunchKernelGGL(k_enc,   dim3(128), dim3(1024), ENC_LDS_FLOATS*4, stream, p);
  hipLaunchKernelGGL(k_hproj, dim3(BATCH), dim3(256), 0, stream, p);
  hipLaunchKernelGGL(k_dec,   dim3(128), dim3(1024), DEC_LDS_FLOATS*4, stream, p);
}

// Round 4
// 5654.544 us; speedup vs baseline: 1.0006x; 1.0006x over previous
//
#include <hip/hip_runtime.h>

#define BATCH 512
#define TT 64
#define II 128

// ---------------- workspace layout (floats) ----------------
#define OFF_Wr_e0 0                         // [512][256] rows: [Wih0(x,pad)|Whh0(h0)]
#define OFF_Wr_e1 (OFF_Wr_e0 + 512*256)     // [512][256] rows: [Wih1(h0)|Whh1(h1)]
#define OFF_Wr_d1 (OFF_Wr_e1 + 512*256)     // [512][256] rows: [dWih1(h0)|dWhh1(h1)]
#define OFF_bs0e  (OFF_Wr_d1 + 512*256)
#define OFF_bs1e  (OFF_bs0e + 512)
#define OFF_bs0d  (OFF_bs1e + 512)
#define OFF_bs1d  (OFF_bs0d + 512)
#define OFF_xprojT (OFF_bs1d + 512)          // [B][64j][128e]
#define OFF_hexp   (OFF_xprojT + BATCH*8192) // [B][64t][128k]
#define OFF_hprojT (OFF_hexp + BATCH*8192)   // [B][128kk][64t]

struct Params {
  const float* input;
  const float *eWih0, *eWhh0, *ebih0, *ebhh0, *eWih1, *eWhh1, *ebih1, *ebhh1;
  const float *dWih0, *dWhh0, *dbih0, *dbhh0, *dWih1, *dWhh1, *dbih1, *dbhh1;
  const float *aW1, *ab1, *aW2, *ab2;
  const float *adW1, *adb1, *adW2, *adb2;
  const float *dinW, *dinb, *projW, *projb;
  float* ws;
  float* out;
};

#define L2E 1.4426950408889634f

__device__ __forceinline__ float exp2f_(float x){ return __builtin_amdgcn_exp2f(x); }
__device__ __forceinline__ float rcp_(float x){ return __builtin_amdgcn_rcpf(x); }
__device__ __forceinline__ float fast_tanh(float x){
  float t = exp2f_(x * 2.8853900817779268f);   // e^{2x}
  return 1.f - 2.f * rcp_(t + 1.f);
}
__device__ __forceinline__ float sigm(float x){
  return rcp_(1.f + exp2f_(-x * L2E));
}
__device__ __forceinline__ float wave_max(float v){
  #pragma unroll
  for (int o = 32; o > 0; o >>= 1) v = fmaxf(v, __shfl_xor(v, o, 64));
  return v;
}
__device__ __forceinline__ float wave_sum(float v){
  #pragma unroll
  for (int o = 32; o > 0; o >>= 1) v += __shfl_xor(v, o, 64);
  return v;
}
// barrier that orders LDS but leaves global (vmcnt) loads/stores in flight.
// All cross-thread communication in the t-loops goes through LDS, so this is safe.
__device__ __forceinline__ void bar_lds(){
  asm volatile("s_waitcnt lgkmcnt(0)\n\ts_barrier" ::: "memory");
}

#define FMA4(W,V0,V1,V2,V3) \
  a0 += (W).x*(V0).x + (W).y*(V0).y + (W).z*(V0).z + (W).w*(V0).w; \
  a1 += (W).x*(V1).x + (W).y*(V1).y + (W).z*(V1).z + (W).w*(V1).w; \
  a2 += (W).x*(V2).x + (W).y*(V2).y + (W).z*(V2).z + (W).w*(V2).w; \
  a3 += (W).x*(V3).x + (W).y*(V3).y + (W).z*(V3).z + (W).w*(V3).w;

// ---------------- prep ----------------
__global__ __launch_bounds__(256) void k_prep(Params p){
  float* ws = p.ws;
  const int gid = blockIdx.x*256 + threadIdx.x;
  const int gsz = gridDim.x*256;
  for (int i = gid; i < 512*256; i += gsz){
    const int j = i >> 8, k = i & 255;
    ws[OFF_Wr_e0 + i] = (k < 128) ? ((k < 127) ? p.eWih0[j*127 + k] : 0.f)
                                  : p.eWhh0[j*128 + (k-128)];
    ws[OFF_Wr_e1 + i] = (k < 128) ? p.eWih1[j*128 + k] : p.eWhh1[j*128 + (k-128)];
    ws[OFF_Wr_d1 + i] = (k < 128) ? p.dWih1[j*128 + k] : p.dWhh1[j*128 + (k-128)];
  }
  for (int i = gid; i < 512; i += gsz){
    ws[OFF_bs0e+i] = p.ebih0[i]+p.ebhh0[i];
    ws[OFF_bs1e+i] = p.ebih1[i]+p.ebhh1[i];
    ws[OFF_bs0d+i] = p.dbih0[i]+p.dbhh0[i];
    ws[OFF_bs1d+i] = p.dbih1[i]+p.dbhh1[i];
  }
}

// ---------------- xprojT ----------------
__global__ __launch_bounds__(256) void k_xproj(Params p){
  __shared__ float xin[64][128];
  __shared__ float w1x[64][64];
  __shared__ float b1s[64];
  const int b = blockIdx.x, tid = threadIdx.x;
  const float* inb = p.input + (size_t)b*(TT*II);
  for (int i = tid; i < 64*128; i += 256){
    const int k = i >> 7, e = i & 127;
    xin[k][e] = (e < 127) ? inb[k*II + 1 + e] : 0.f;
  }
  for (int i = tid; i < 64*64; i += 256){
    const int j = i >> 6, k = i & 63;
    w1x[j][k] = p.aW1[j*320 + 256 + k];
  }
  if (tid < 64) b1s[tid] = p.ab1[tid];
  __syncthreads();
  float* outb = p.ws + OFF_xprojT + (size_t)b*8192;
  for (int i = tid; i < 64*128; i += 256){
    const int j = i >> 7, e = i & 127;
    float acc = b1s[j];
    #pragma unroll 8
    for (int k = 0; k < 64; ++k) acc += xin[k][e] * w1x[j][k];
    outb[i] = acc;
  }
}

// ---------------- hprojT ----------------
__global__ __launch_bounds__(256) void k_hproj(Params p){
  __shared__ float hx[64][129];
  __shared__ float bs[128];
  const int b = blockIdx.x, tid = threadIdx.x;
  const float* hb = p.ws + OFF_hexp + (size_t)b*8192;
  for (int i = tid; i < 64*128; i += 256) hx[i>>7][i&127] = hb[i];
  if (tid < 128) bs[tid] = p.adb1[tid];
  __syncthreads();
  float* outb = p.ws + OFF_hprojT + (size_t)b*8192;
  for (int i = tid; i < 128*64; i += 256){
    const int kk = i >> 6, t2 = i & 63;
    const float* w = p.adW1 + kk*384 + 256;
    float acc = bs[kk];
    #pragma unroll 8
    for (int k = 0; k < 128; ++k) acc += hx[t2][k] * w[k];
    outb[i] = acc;
  }
}

// ---------------- encoder ----------------
// LDS floats: xp 32768 | Se 2048 | c0s 512 | gpA 2048 | gpB 2048 | g01s 256
//             w2 64 | pm 16 | psu 16   = 39776 (159,104 B)
#define ENC_LDS_FLOATS 39776
__global__ __launch_bounds__(1024, 4) void k_enc(Params p){
  extern __shared__ float sm[];
  float* xp   = sm;
  float* Se   = xp + 32768;    // [bb][x|h0|h1|c1] 4x512
  float* c0s  = Se + 2048;
  float* gpA  = c0s + 512;
  float* gpB  = gpA + 2048;
  float* g01s = gpB + 2048;    // [bb*64+jj]
  float* w2   = g01s + 256;
  float* pm   = w2 + 64;
  float* psu  = pm + 16;
  const int tid = threadIdx.x;
  const int b0 = blockIdx.x*4;
  float* ws = p.ws;

  { const float4* xsrc = (const float4*)(ws + OFF_xprojT + (size_t)b0*8192);
    float4* xdst = (float4*)xp;
    for (int i = tid; i < 8192; i += 1024) xdst[i] = xsrc[i]; }
  for (int i = tid; i < 2048; i += 1024) Se[i] = 0.f;
  if (tid < 512) c0s[tid] = 0.f;
  if (tid < 64) w2[tid] = p.aW2[tid];
  const float b2 = p.ab2[0];

  const int bbW = tid >> 8;                 // wave-group batch
  const int wvq = (tid >> 6) & 3;
  const int kqE = tid & 3, oE = tid >> 2, jjE = oE & 63;   // E1
  const int jhE = tid & 1, eE = (tid >> 1) & 127;          // E2
  const int jG = tid & 511, khG = tid >> 9;                // gate GEMMs
  const float bias0 = ws[OFF_bs0e + jG];
  const float bias1 = ws[OFF_bs1e + jG];
  const float4* wE1 = (const float4*)(p.aW1 + jjE*320 + kqE*64);          // 16 f4
  const float4* wE3 = (const float4*)(ws + OFF_Wr_e0 + (jG<<8) + (khG<<7)); // 32 f4
  const float4* wE4 = (const float4*)(ws + OFF_Wr_e1 + (jG<<8) + (khG<<7)); // 32 f4
  const float* xrow = p.input + (size_t)(b0+bbW)*8192 + 1 + eE;
  // persistent weight prefetch (t-invariant)
  float4 pfE1[4], pfE3[4], pfE4[4];
  #pragma unroll
  for (int i = 0; i < 4; ++i){ pfE1[i]=wE1[i]; pfE3[i]=wE3[i]; pfE4[i]=wE4[i]; }
  __syncthreads();

  for (int t = 0; t < TT; ++t){
    // --- E1: g01[bb][jj], 4 lanes/output (K=64 each), shfl combine
    {
      const float4* s1 = (const float4*)(Se + bbW*512 + 256 + kqE*64);
      float a = 0.f;
      #pragma unroll
      for (int kg = 0; kg < 4; ++kg){ float4 w = pfE1[kg], x = s1[kg];
        a += w.x*x.x + w.y*x.y + w.z*x.z + w.w*x.w; }
      #pragma unroll
      for (int kg = 4; kg < 16; ++kg){ float4 w = wE1[kg], x = s1[kg];
        a += w.x*x.x + w.y*x.y + w.z*x.z + w.w*x.w; }
      a += __shfl_xor(a, 1, 64);
      a += __shfl_xor(a, 2, 64);
      if (kqE == 0) g01s[oE] = a;
    }
    bar_lds();
    // --- E2a: logits (pair-split over j), softmax wave partials
    float accL;
    {
      const float* xpe = xp + bbW*8192 + eE;
      const float* gg = g01s + bbW*64 + jhE*32;
      const float* w2p = w2 + jhE*32;
      float a = 0.f;
      #pragma unroll 8
      for (int q = 0; q < 32; ++q)
        a += w2p[q] * fast_tanh(xpe[(jhE*32+q)*128] + gg[q]);
      a += __shfl_xor(a, 1, 64);
      a += b2;
      if (eE == 127) a = -3.0e38f;
      accL = a;
      const float m = wave_max(a);
      const float pe = exp2f_((a - m)*L2E);
      const float s = wave_sum(pe)*0.5f;   // pair-duplicated
      if ((tid & 63) == 0){ pm[bbW*4+wvq] = m; psu[bbW*4+wvq] = s; }
    }
    bar_lds();
    // --- E2c: finish softmax, Se.x = a * x_t (pair-dup writes identical)
    {
      const float m0=pm[bbW*4],m1=pm[bbW*4+1],m2=pm[bbW*4+2],m3=pm[bbW*4+3];
      const float gm = fmaxf(fmaxf(m0,m1),fmaxf(m2,m3));
      const float tot = psu[bbW*4]*exp2f_((m0-gm)*L2E) + psu[bbW*4+1]*exp2f_((m1-gm)*L2E)
                      + psu[bbW*4+2]*exp2f_((m2-gm)*L2E) + psu[bbW*4+3]*exp2f_((m3-gm)*L2E);
      const float a = exp2f_((accL-gm)*L2E)*rcp_(tot);
      float xv = 0.f;
      if (eE < 127) xv = xrow[t*128] * a;
      Se[bbW*512 + eE] = xv;
    }
    bar_lds();
    // --- E3: layer0 gates, operand Se[0..255] (x|h0)
    {
      float a0,a1,a2,a3; a0=a1=a2=a3 = khG ? 0.f : bias0;
      const float4* x0 = (const float4*)(Se + (khG<<7));
      const float4* x1 = x0 + 128; const float4* x2 = x0 + 256; const float4* x3 = x0 + 384;
      #pragma unroll
      for (int kg = 0; kg < 4; ++kg){ float4 w = pfE3[kg];
        float4 v0=x0[kg],v1=x1[kg],v2=x2[kg],v3=x3[kg]; FMA4(w,v0,v1,v2,v3) }
      #pragma unroll 7
      for (int kg = 4; kg < 32; ++kg){ float4 w = wE3[kg];
        float4 v0=x0[kg],v1=x1[kg],v2=x2[kg],v3=x3[kg]; FMA4(w,v0,v1,v2,v3) }
      float* gp = khG ? gpB : gpA;
      gp[jG]=a0; gp[512+jG]=a1; gp[1024+jG]=a2; gp[1536+jG]=a3;
    }
    bar_lds();
    // --- A0: update h0,c0
    if (tid < 512){
      const int bb = tid>>7, u = tid&127;
      const float* gA = gpA + bb*512; const float* gB = gpB + bb*512;
      const float gi=gA[u]+gB[u], gf=gA[128+u]+gB[128+u];
      const float gg2=gA[256+u]+gB[256+u], go=gA[384+u]+gB[384+u];
      const float c = sigm(gf)*c0s[tid] + sigm(gi)*fast_tanh(gg2);
      c0s[tid] = c;
      Se[bb*512 + 128 + u] = sigm(go)*fast_tanh(c);
    }
    bar_lds();
    // --- E4: layer1 gates, operand Se[128..383] (h0|h1)
    {
      float a0,a1,a2,a3; a0=a1=a2=a3 = khG ? 0.f : bias1;
      const float4* x0 = (const float4*)(Se + 128 + (khG<<7));
      const float4* x1 = x0 + 128; const float4* x2 = x0 + 256; const float4* x3 = x0 + 384;
      #pragma unroll
      for (int kg = 0; kg < 4; ++kg){ float4 w = pfE4[kg];
        float4 v0=x0[kg],v1=x1[kg],v2=x2[kg],v3=x3[kg]; FMA4(w,v0,v1,v2,v3) }
      #pragma unroll 7
      for (int kg = 4; kg < 32; ++kg){ float4 w = wE4[kg];
        float4 v0=x0[kg],v1=x1[kg],v2=x2[kg],v3=x3[kg]; FMA4(w,v0,v1,v2,v3) }
      float* gp = khG ? gpB : gpA;
      gp[jG]=a0; gp[512+jG]=a1; gp[1024+jG]=a2; gp[1536+jG]=a3;
    }
    bar_lds();
    // --- A1: update h1,c1, nontemporal hexp store
    if (tid < 512){
      const int bb = tid>>7, u = tid&127;
      const float* gA = gpA + bb*512; const float* gB = gpB + bb*512;
      const float gi=gA[u]+gB[u], gf=gA[128+u]+gB[128+u];
      const float gg2=gA[256+u]+gB[256+u], go=gA[384+u]+gB[384+u];
      const float c = sigm(gf)*Se[bb*512+384+u] + sigm(gi)*fast_tanh(gg2);
      Se[bb*512+384+u] = c;
      const float h = sigm(go)*fast_tanh(c);
      Se[bb*512+256+u] = h;
      __builtin_nontemporal_store(h, ws + OFF_hexp + (size_t)(b0+bb)*8192 + t*128 + u);
    }
    bar_lds();
  }
}

// ---------------- decoder ----------------
// LDS floats: hp 33280 | Sd 1536 | c0s 512 | gpA 2048 | gpB 2048 | parts 512
//             g01d 512 | lraw 256 | pm 16 | psu 16 | dpart 16 | wd2 128 = 40880 (163,520 B)
#define DEC_LDS_FLOATS 40880
__global__ __launch_bounds__(1024, 4) void k_dec(Params p){
  extern __shared__ float sm[];
  float* hp    = sm;             // [bb][kk][65] padded
  float* Sd    = hp + 33280;     // [bb][h0|h1|c1] 4x384
  float* c0s   = Sd + 1536;
  float* gpA   = c0s + 512;
  float* gpB   = gpA + 2048;
  float* parts = gpB + 2048;     // [bb][128]
  float* g01d  = parts + 512;    // [bb][128]
  float* lraw  = g01d + 512;     // [bb][64] raw logits, then abuf in-place
  float* pm    = lraw + 256;
  float* psu   = pm + 16;
  float* dpart = psu + 16;
  float* wd2   = dpart + 16;
  const int tid = threadIdx.x;
  const int b0 = blockIdx.x*4;
  float* ws = p.ws;

  { const float* hsrc = ws + OFF_hprojT + (size_t)b0*8192;
    for (int i = tid; i < 32768; i += 1024){
      const int bb = i>>13, kk = (i>>6)&127, tl = i&63;
      hp[bb*8320 + kk*65 + tl] = hsrc[i];
    } }
  for (int i = tid; i < 1536; i += 1024) Sd[i] = 0.f;
  if (tid < 512) c0s[tid] = 0.f;
  if (tid < 128) wd2[tid] = p.adW2[tid];
  const float bd2 = p.adb2[0];

  const int bbW = tid >> 8, wvq = (tid >> 6) & 3;
  const int khD = tid & 1, kkD = (tid >> 1) & 127;          // D1
  const int kq4 = tid & 3, o4 = tid >> 2, tl4 = o4 & 63;    // D2a
  const int thC = tid & 1, hC = (tid >> 1) & 127;           // D2c
  const int jG = tid & 511, khG = tid >> 9;
  const float bias0d = ws[OFF_bs0d + jG];
  const float bias1d = ws[OFF_bs1d + jG];
  const float dW0j = p.dWih0[jG];
  const float dinw_h = p.dinW[hC];
  const float dinw128 = p.dinW[128], dinbv = p.dinb[0];
  const float4* wD1 = (const float4*)(p.adW1 + kkD*384 + khD*128);          // 32 f4
  const float4* wD3 = (const float4*)(p.dWhh0 + (jG<<7) + (khG<<6));        // 16 f4
  const float4* wD4 = (const float4*)(ws + OFF_Wr_d1 + (jG<<8) + (khG<<7)); // 32 f4
  const float* heB = ws + OFF_hexp + (size_t)(b0+bbW)*8192 + thC*4096 + hC;
  float4 pfD1[4], pfD3[4], pfD4[4];
  #pragma unroll
  for (int i = 0; i < 4; ++i){ pfD1[i]=wD1[i]; pfD3[i]=wD3[i]; pfD4[i]=wD4[i]; }
  __syncthreads();

  for (int t = 0; t < TT; ++t){
    // --- D1: g01d[bb][kk], pair-split K over [h1|c1], shfl combine
    {
      const float4* sx = (const float4*)(Sd + bbW*384 + 128 + khD*128);
      float a = 0.f;
      #pragma unroll
      for (int kg = 0; kg < 4; ++kg){ float4 w = pfD1[kg], x = sx[kg];
        a += w.x*x.x + w.y*x.y + w.z*x.z + w.w*x.w; }
      #pragma unroll 7
      for (int kg = 4; kg < 32; ++kg){ float4 w = wD1[kg], x = sx[kg];
        a += w.x*x.x + w.y*x.y + w.z*x.z + w.w*x.w; }
      a += __shfl_xor(a, 1, 64);
      if (khD == 0) g01d[bbW*128 + kkD] = a;
    }
    bar_lds();
    // --- D2a: logits (4 lanes/output over kk), softmax wave partials
    float lacc;
    {
      const float* hpb = hp + bbW*8320 + tl4;
      const float* gg = g01d + bbW*128;
      float a = 0.f;
      #pragma unroll 8
      for (int q = 0; q < 32; ++q){
        const int kk = q*4 + kq4;
        a += wd2[kk] * fast_tanh(hpb[kk*65] + gg[kk]);
      }
      a += __shfl_xor(a, 1, 64);
      a += __shfl_xor(a, 2, 64);
      a += bd2;
      lacc = a;
      if (kq4 == 0) lraw[o4] = a;
      const float m = wave_max(a);
      const float pe = exp2f_((a-m)*L2E);
      const float s = wave_sum(pe)*0.25f;   // 4x duplicated
      if ((tid&63)==0){ pm[bbW*4+wvq]=m; psu[bbW*4+wvq]=s; }
    }
    bar_lds();
    // --- D2b: abuf in-place over lraw
    if (tid < 256){
      const int bb = tid>>6;
      const float m0=pm[bb*4],m1=pm[bb*4+1],m2=pm[bb*4+2],m3=pm[bb*4+3];
      const float gm = fmaxf(fmaxf(m0,m1),fmaxf(m2,m3));
      const float tot = psu[bb*4]*exp2f_((m0-gm)*L2E)+psu[bb*4+1]*exp2f_((m1-gm)*L2E)
                      +psu[bb*4+2]*exp2f_((m2-gm)*L2E)+psu[bb*4+3]*exp2f_((m3-gm)*L2E);
      lraw[tid] = exp2f_((lraw[tid]-gm)*L2E)*rcp_(tot);
    }
    bar_lds();
    // --- D2c: parts (pair-split over t'), shfl combine, din partial folded
    {
      const float* av = lraw + bbW*64 + thC*32;
      float a = 0.f;
      #pragma unroll 8
      for (int q = 0; q < 32; ++q) a += av[q] * heB[q*128];
      a += __shfl_xor(a, 1, 64);
      if (thC == 0) parts[bbW*128 + hC] = a;
      float v = a * dinw_h;
      v = wave_sum(v)*0.5f;    // pair-duplicated
      if ((tid&63)==0) dpart[bbW*4+wvq] = v;
    }
    bar_lds();
    // --- D3: layer0 gates (K=128 h0 + rank-1 din), din dup-computed
    {
      const float xd0 = p.input[(size_t)(b0+0)*8192 + t*128];
      const float xd1 = p.input[(size_t)(b0+1)*8192 + t*128];
      const float xd2 = p.input[(size_t)(b0+2)*8192 + t*128];
      const float xd3 = p.input[(size_t)(b0+3)*8192 + t*128];
      const float dn0 = dpart[0]+dpart[1]+dpart[2]+dpart[3] + xd0*dinw128 + dinbv;
      const float dn1 = dpart[4]+dpart[5]+dpart[6]+dpart[7] + xd1*dinw128 + dinbv;
      const float dn2 = dpart[8]+dpart[9]+dpart[10]+dpart[11] + xd2*dinw128 + dinbv;
      const float dn3 = dpart[12]+dpart[13]+dpart[14]+dpart[15] + xd3*dinw128 + dinbv;
      float a0,a1,a2,a3;
      if (khG){ a0=a1=a2=a3=0.f; }
      else { a0=bias0d+dn0*dW0j; a1=bias0d+dn1*dW0j; a2=bias0d+dn2*dW0j; a3=bias0d+dn3*dW0j; }
      const float4* x0 = (const float4*)(Sd + (khG<<6));
      const float4* x1 = x0 + 96; const float4* x2 = x0 + 192; const float4* x3 = x0 + 288;
      #pragma unroll
      for (int kg = 0; kg < 4; ++kg){ float4 w = pfD3[kg];
        float4 v0=x0[kg],v1=x1[kg],v2=x2[kg],v3=x3[kg]; FMA4(w,v0,v1,v2,v3) }
      #pragma unroll
      for (int kg = 4; kg < 16; ++kg){ float4 w = wD3[kg];
        float4 v0=x0[kg],v1=x1[kg],v2=x2[kg],v3=x3[kg]; FMA4(w,v0,v1,v2,v3) }
      float* gp = khG ? gpB : gpA;
      gp[jG]=a0; gp[512+jG]=a1; gp[1024+jG]=a2; gp[1536+jG]=a3;
    }
    bar_lds();
    // --- A2: update h0,c0
    if (tid < 512){
      const int bb = tid>>7, u = tid&127;
      const float* gA = gpA + bb*512; const float* gB = gpB + bb*512;
      const float gi=gA[u]+gB[u], gf=gA[128+u]+gB[128+u];
      const float gg2=gA[256+u]+gB[256+u], go=gA[384+u]+gB[384+u];
      const float c = sigm(gf)*c0s[tid] + sigm(gi)*fast_tanh(gg2);
      c0s[tid] = c;
      Sd[bb*384 + u] = sigm(go)*fast_tanh(c);
    }
    bar_lds();
    // --- D4: layer1 gates (K=256 h0|h1)
    {
      float a0,a1,a2,a3; a0=a1=a2=a3 = khG ? 0.f : bias1d;
      const float4* x0 = (const float4*)(Sd + (khG<<7));
      const float4* x1 = x0 + 96; const float4* x2 = x0 + 192; const float4* x3 = x0 + 288;
      #pragma unroll
      for (int kg = 0; kg < 4; ++kg){ float4 w = pfD4[kg];
        float4 v0=x0[kg],v1=x1[kg],v2=x2[kg],v3=x3[kg]; FMA4(w,v0,v1,v2,v3) }
      #pragma unroll 7
      for (int kg = 4; kg < 32; ++kg){ float4 w = wD4[kg];
        float4 v0=x0[kg],v1=x1[kg],v2=x2[kg],v3=x3[kg]; FMA4(w,v0,v1,v2,v3) }
      float* gp = khG ? gpB : gpA;
      gp[jG]=a0; gp[512+jG]=a1; gp[1024+jG]=a2; gp[1536+jG]=a3;
    }
    bar_lds();
    // --- A3: update h1,c1
    if (tid < 512){
      const int bb = tid>>7, u = tid&127;
      const float* gA = gpA + bb*512; const float* gB = gpB + bb*512;
      const float gi=gA[u]+gB[u], gf=gA[128+u]+gB[128+u];
      const float gg2=gA[256+u]+gB[256+u], go=gA[384+u]+gB[384+u];
      const float c = sigm(gf)*Sd[bb*384+256+u] + sigm(gi)*fast_tanh(gg2);
      Sd[bb*384+256+u] = c;
      Sd[bb*384+128+u] = sigm(go)*fast_tanh(c);
    }
    bar_lds();
  }
  // --- final projection
  if (tid < 256){
    const int bb = tid>>6, l = tid&63;
    float v = Sd[bb*384+128+l]*p.projW[l] + Sd[bb*384+192+l]*p.projW[64+l]
            + parts[bb*128+l]*p.projW[128+l] + parts[bb*128+64+l]*p.projW[192+l];
    v = wave_sum(v);
    if (l == 0) p.out[b0 + bb] = v + p.projb[0];
  }
}

extern "C" void kernel_launch(void* const* d_in, const int* in_sizes, int n_in,
                              void* d_out, int out_size, void* d_ws, size_t ws_size,
                              hipStream_t stream){
  Params p;
  p.input = (const float*)d_in[0];
  p.eWih0=(const float*)d_in[1];  p.eWhh0=(const float*)d_in[2];
  p.ebih0=(const float*)d_in[3];  p.ebhh0=(const float*)d_in[4];
  p.eWih1=(const float*)d_in[5];  p.eWhh1=(const float*)d_in[6];
  p.ebih1=(const float*)d_in[7];  p.ebhh1=(const float*)d_in[8];
  p.dWih0=(const float*)d_in[9];  p.dWhh0=(const float*)d_in[10];
  p.dbih0=(const float*)d_in[11]; p.dbhh0=(const float*)d_in[12];
  p.dWih1=(const float*)d_in[13]; p.dWhh1=(const float*)d_in[14];
  p.dbih1=(const float*)d_in[15]; p.dbhh1=(const float*)d_in[16];
  p.aW1=(const float*)d_in[17];   p.ab1=(const float*)d_in[18];
  p.aW2=(const float*)d_in[19];   p.ab2=(const float*)d_in[20];
  p.adW1=(const float*)d_in[21];  p.adb1=(const float*)d_in[22];
  p.adW2=(const float*)d_in[23];  p.adb2=(const float*)d_in[24];
  p.dinW=(const float*)d_in[25];  p.dinb=(const float*)d_in[26];
  p.projW=(const float*)d_in[27]; p.projb=(const float*)d_in[28];
  p.ws = (float*)d_ws;
  p.out = (float*)d_out;

  (void)hipFuncSetAttribute(reinterpret_cast<const void*>(k_enc),
      hipFuncAttributeMaxDynamicSharedMemorySize, ENC_LDS_FLOATS*4);
  (void)hipFuncSetAttribute(reinterpret_cast<const void*>(k_dec),
      hipFuncAttributeMaxDynamicSharedMemorySize, DEC_LDS_FLOATS*4);

  hipLaunchKernelGGL(k_prep,  dim3(128), dim3(256), 0, stream, p);
  hipLaunchKernelGGL(k_xproj, dim3(BATCH), dim3(256), 0, stream, p);
  hipLaunchKernelGGL(k_enc,   dim3(128), dim3(1024), ENC_LDS_FLOATS*4, stream, p);
  hipLaunchKernelGGL(k_hproj, dim3(BATCH), dim3(256), 0, stream, p);
  hipLaunchKernelGGL(k_dec,   dim3(128), dim3(1024), DEC_LDS_FLOATS*4, stream, p);
}